// Round 3
// baseline (18415.146 us; speedup 1.0000x reference)
//
#include <hip/hip_runtime.h>
#include <stdint.h>

// Fused 3-layer GRU pipeline: B=32, T=2048, I=12, H=512.
// 96 persistent WGs (32/layer, 16 hidden units each), 2 independent waves/WG
// (batch halves). Tag-validated speculative loads merge sync+data into one L3
// round trip: producer wave does {data stores, vmcnt(0), tag:=t+1}; consumer
// loads data+tags together and validates per 16B chunk, retrying if stale.
// No in-loop barriers. All cross-WG traffic device-coherent (sc0 sc1).

#define B_ 32
#define T_ 2048
#define H_ 512
#define R_ 128          // ring depth (steps)

typedef __attribute__((ext_vector_type(8))) short s8v;     // 8 bf16 (4 VGPR)
typedef __attribute__((ext_vector_type(4))) float f4v;     // MFMA acc
typedef __attribute__((ext_vector_type(4))) uint32_t u32x4;

__device__ __forceinline__ uint16_t f2bf(float f){ return __builtin_bit_cast(uint16_t, (__bf16)f); }
__device__ __forceinline__ float bf2f(uint16_t b){ return __builtin_bit_cast(float, ((uint32_t)b)<<16); }

__device__ __forceinline__ s8v pack8(const float* f){
  s8v r;
  #pragma unroll
  for (int i=0;i<8;++i) r[i] = (short)f2bf(f[i]);
  return r;
}
__device__ __forceinline__ f4v mfma16(s8v a, s8v b, f4v c){
  return __builtin_amdgcn_mfma_f32_16x16x32_bf16(a,b,c,0,0,0);
}
#if __has_builtin(__builtin_amdgcn_rcpf)
__device__ __forceinline__ float rcp_(float x){ return __builtin_amdgcn_rcpf(x); }
#else
__device__ __forceinline__ float rcp_(float x){ return 1.0f/x; }
#endif
__device__ __forceinline__ float sigm(float s){ return rcp_(1.f + __expf(-s)); }
__device__ __forceinline__ float tanh2(float v){ return 1.f - 2.f*rcp_(1.f + __expf(2.f*v)); }

// device-coherent ops (bypass non-coherent per-XCD L2, served by L3)
__device__ __forceinline__ u32x4 load_x4_sc(const void* p){
  u32x4 r;
  asm volatile("global_load_dwordx4 %0, %1, off sc0 sc1" : "=v"(r) : "v"(p) : "memory");
  return r;
}
__device__ __forceinline__ uint32_t load_u32_sc(const void* p){
  uint32_t r;
  asm volatile("global_load_dword %0, %1, off sc0 sc1" : "=v"(r) : "v"(p) : "memory");
  return r;
}
__device__ __forceinline__ uint32_t load_u32_sc_wait(const void* p){
  uint32_t r;
  asm volatile("global_load_dword %0, %1, off sc0 sc1\n\ts_waitcnt vmcnt(0)"
               : "=v"(r) : "v"(p) : "memory");
  return r;
}
__device__ __forceinline__ void store_s16_sc(void* p, uint32_t v){
  asm volatile("global_store_short %0, %1, off sc0 sc1" :: "v"(p), "v"(v) : "memory");
}
__device__ __forceinline__ void store_u32_sc(void* p, uint32_t v){
  asm volatile("global_store_dword %0, %1, off sc0 sc1" :: "v"(p), "v"(v) : "memory");
}

__global__ void init_kernel(const float* __restrict__ vel_init,
    const float* __restrict__ w0, const float* __restrict__ b0,
    const float* __restrict__ w1, const float* __restrict__ b1,
    const float* __restrict__ w2, const float* __restrict__ b2,
    float* __restrict__ h0f, uint16_t* __restrict__ h0b, uint32_t* tags)
{
  const int l = blockIdx.x, tid = threadIdx.x;
  const float* w  = (l==0)?w0:((l==1)?w1:w2);
  const float* bb = (l==0)?b0:((l==1)?b1:b2);
  for (int idx = tid; idx < B_*H_; idx += 256){
    int b = idx >> 9, j = idx & 511;
    float s = bb[j] + vel_init[b*3+0]*w[j*3+0] + vel_init[b*3+1]*w[j*3+1]
                    + vel_init[b*3+2]*w[j*3+2];
    h0f[(size_t)l*(B_*H_) + idx] = s;
    h0b[(size_t)l*(B_*H_) + idx] = f2bf(s);
  }
  if (l == 0 && tid < 192) tags[tid] = 0;   // 3 layers x 64 waves
}

struct ScanParams {
  const float* x;
  const float* wih[3];
  const float* whh[3];
  const float* bih[3];
  const float* bhh[3];
  const float* h0f;
  const uint16_t* h0b;
  uint16_t* ring0;   // [R_][B][H] bf16, layer0 -> layer1 (also layer0 h history)
  uint16_t* ring1;   // [R_][B][H] bf16, layer1 -> layer2 (also layer1 h history)
  uint16_t* out2;    // [T][B][H] bf16, layer2 output (+ its own h history)
  uint32_t* tags;    // [3][64]: per (layer, wg*2+mt) completed-steps counter
};

__global__ __launch_bounds__(128, 1) void fused_scan(ScanParams P)
{
  const int tid  = threadIdx.x;
  const int lane = tid & 63;
  const int mt   = tid >> 6;            // wave = batch half (0/1)
  const int wgid = blockIdx.x;          // 0..95
  const int layer = wgid >> 5;          // 0..2
  const int wg   = wgid & 31;
  const int j0   = wg * 16;
  const int u    = lane & 15;           // unit col / A row
  const int lq   = lane >> 4;           // 0..3
  const int ko   = lq * 8;              // k octet (elements)
  const int koq  = lq >> 1;             // which 16-unit block half
  const int bd   = lq * 4;              // D row base

  __shared__ uint16_t lds[48*512];      // wih slice (layers 1,2)
  __shared__ char pad_[49152];          // force 1 WG/CU (96KB LDS total)
  if (P.x == nullptr) ((volatile char*)pad_)[0] = 1;   // never true; keeps pad_ alive

  const float* wih = P.wih[layer];
  const float* whh = P.whh[layer];
  const float* bih = P.bih[layer];
  const float* bhh = P.bhh[layer];

  const float bs0 = bih[0*H_ + j0 + u] + bhh[0*H_ + j0 + u];
  const float bs1 = bih[1*H_ + j0 + u] + bhh[1*H_ + j0 + u];
  const float bi2 = bih[2*H_ + j0 + u];
  const float bh2 = bhh[2*H_ + j0 + u];

  // W_hh B-fragments resident in VGPRs (48 frags = 192 VGPR/lane)
  s8v whhf[3][16];
  #pragma unroll
  for (int nt=0; nt<3; ++nt){
    #pragma unroll
    for (int ks=0; ks<16; ++ks){
      const float* wp = whh + (size_t)(nt*H_ + j0 + u)*H_ + ks*32 + ko;
      float tmp[8];
      #pragma unroll
      for (int i=0;i<8;++i) tmp[i] = wp[i];
      whhf[nt][ks] = pack8(tmp);
    }
  }

  s8v w0f[3];
  if (layer == 0){
    #pragma unroll
    for (int nt=0; nt<3; ++nt){
      float tmp[8];
      #pragma unroll
      for (int i=0;i<8;++i){
        int k = ko + i;
        tmp[i] = (k < 12) ? wih[(size_t)(nt*H_ + j0 + u)*12 + k] : 0.f;
      }
      w0f[nt] = pack8(tmp);
    }
  } else {
    // stage W_ih slice to LDS, bf16, XOR-swizzled: mask = ((g&7)^((g>>3)&1)<<1)<<4
    // (bit-5 term separates rows g and g+8 -> no same-bank aliasing)
    for (int e = tid; e < (48*512)/8; e += 128) {
      int idx = e * 8;
      int g = idx >> 9, k = idx & 511;
      const float* wp = wih + (size_t)((g>>4)*H_ + j0 + (g&15))*H_ + k;
      float tmp[8];
      #pragma unroll
      for (int i=0;i<8;++i) tmp[i] = wp[i];
      s8v v = pack8(tmp);
      uint32_t msk = (uint32_t)((((g&7) ^ (((g>>3)&1)<<1))) << 4);
      uint32_t off = (uint32_t)g*1024u + ((((uint32_t)k)*2u) ^ msk);
      *(u32x4*)((char*)lds + off) = __builtin_bit_cast(u32x4, v);
    }
  }
  __syncthreads();

  uint32_t* towntag = P.tags + layer*64;
  const uint32_t* tprev = (layer>0) ? (P.tags + (layer-1)*64) : nullptr;
  const uint32_t* tcons = (layer<2) ? (P.tags + (layer+1)*64) : nullptr;
  const uint16_t* inring = (layer==1) ? P.ring0 : P.ring1;  // layer0 unused
  uint16_t* outbuf = (layer==0) ? P.ring0 : ((layer==1) ? P.ring1 : P.out2);
  const bool outlin = (layer == 2);

  // fp32 hidden-state carry
  float hold[4];
  #pragma unroll
  for (int r=0;r<4;++r)
    hold[r] = P.h0f[(size_t)layer*(B_*H_) + (size_t)(mt*16 + bd + r)*H_ + j0 + u];

  const uint32_t sw  = (uint32_t)((((u&7) ^ (((u>>3)&1)<<1))) << 4);
  const uint32_t gb0 = (uint32_t)((0*16 + u) * 1024);
  const uint32_t gb1 = (uint32_t)((1*16 + u) * 1024);
  const uint32_t gb2 = (uint32_t)((2*16 + u) * 1024);
  const uint32_t koB = (uint32_t)(ko * 2);

  int bp_until = R_ - 1;   // ring-overwrite safe horizon (cached consumer min)

  for (int t = 0; t < T_; ++t) {
    f4v ac0 = {0,0,0,0}, ac1 = {0,0,0,0}, axn = {0,0,0,0}, ahn = {0,0,0,0};

    // ---- layer-0 x-part: off the critical path ----
    if (layer == 0) {
      const float* xp = P.x + ((size_t)(mt*16 + u)*T_ + (size_t)t)*12;
      float4 lo  = *(const float4*)(xp);
      float4 md  = *(const float4*)(xp + 4);
      float4 hi4 = *(const float4*)(xp + 8);
      float xv[8];
      xv[0] = (ko==0) ? lo.x : hi4.x;  xv[1] = (ko==0) ? lo.y : hi4.y;
      xv[2] = (ko==0) ? lo.z : hi4.z;  xv[3] = (ko==0) ? lo.w : hi4.w;
      xv[4] = (ko==0) ? md.x : 0.f;    xv[5] = (ko==0) ? md.y : 0.f;
      xv[6] = (ko==0) ? md.z : 0.f;    xv[7] = (ko==0) ? md.w : 0.f;
      // (ko>=16 lanes read garbage but their w0f rows are zero)
      s8v a = pack8(xv);
      ac0 = mfma16(a, w0f[0], ac0);
      ac1 = mfma16(a, w0f[1], ac1);
      axn = mfma16(a, w0f[2], axn);
    }

    // ---- ring backpressure (layers 0,1): cached consumer-min, rare poll ----
    if (tcons && t > bp_until) {
      while (1) {
        int c = (int)load_u32_sc_wait(tcons + 2*(lane&31) + mt);
        #pragma unroll
        for (int off=16; off>0; off>>=1){
          int c2 = __shfl_xor(c, off, 64);
          c = (c2 < c) ? c2 : c;
        }
        if (t <= c + R_ - 1) { bp_until = c + R_ - 1; break; }
      }
    }

    // ---- speculative load + per-chunk tag validation (one L3 RT typical) ----
    const uint16_t* xin = (layer > 0)
        ? (inring + (size_t)(t & (R_-1))*(B_*H_) + (size_t)(mt*16+u)*H_ + ko)
        : nullptr;
    const uint16_t* hsrc = (t == 0)
        ? (P.h0b + (size_t)layer*(B_*H_))
        : (outlin ? (P.out2 + (size_t)(t-1)*(B_*H_))
                  : (outbuf + (size_t)((t-1) & (R_-1))*(B_*H_)));
    const uint16_t* hp = hsrc + (size_t)(mt*16+u)*H_ + ko;

    u32x4 xa[16], ha[16];
    uint32_t xt[16], ht[16];
    while (1) {
      if (layer > 0) {
        #pragma unroll
        for (int ks=0; ks<16; ++ks) xa[ks] = load_x4_sc(xin + ks*32);
        #pragma unroll
        for (int ks=0; ks<16; ++ks) xt[ks] = load_u32_sc(tprev + 4*ks + 2*koq + mt);
      }
      #pragma unroll
      for (int ks=0; ks<16; ++ks) ha[ks] = load_x4_sc(hp + ks*32);
      if (t > 0) {
        #pragma unroll
        for (int ks=0; ks<16; ++ks) ht[ks] = load_u32_sc(towntag + 4*ks + 2*koq + mt);
      }
      asm volatile("s_waitcnt vmcnt(0)" ::: "memory");
      __builtin_amdgcn_sched_barrier(0);
      bool ok = true;
      if (layer > 0) {
        #pragma unroll
        for (int ks=0; ks<16; ++ks) ok = ok && ((int)xt[ks] >= t+1);
      }
      if (t > 0) {
        #pragma unroll
        for (int ks=0; ks<16; ++ks) ok = ok && ((int)ht[ks] >= t);
      }
      if (__ballot(ok) == ~0ull) break;
    }

    // ---- x-part MFMAs (layers 1,2) ----
    if (layer > 0) {
      #pragma unroll
      for (int ks=0; ks<16; ++ks){
        s8v a = __builtin_bit_cast(s8v, xa[ks]);
        uint32_t kk = ((uint32_t)(ks*64) + koB) ^ sw;
        s8v w0 = *(const s8v*)((const char*)lds + gb0 + kk);
        s8v w1 = *(const s8v*)((const char*)lds + gb1 + kk);
        s8v w2 = *(const s8v*)((const char*)lds + gb2 + kk);
        ac0 = mfma16(a, w0, ac0);
        ac1 = mfma16(a, w1, ac1);
        axn = mfma16(a, w2, axn);
      }
    }

    // ---- h-part MFMAs ----
    #pragma unroll
    for (int ks=0; ks<16; ++ks){
      s8v a = __builtin_bit_cast(s8v, ha[ks]);
      ac0 = mfma16(a, whhf[0][ks], ac0);
      ac1 = mfma16(a, whhf[1][ks], ac1);
      ahn = mfma16(a, whhf[2][ks], ahn);
    }

    // ---- gates (lane-local) + coherent store ----
    uint16_t* orow = outbuf
        + (outlin ? (size_t)t*(B_*H_) : (size_t)(t & (R_-1))*(B_*H_))
        + (size_t)(mt*16 + bd)*H_ + j0 + u;
    #pragma unroll
    for (int r=0;r<4;++r){
      float rg = sigm(ac0[r] + bs0);
      float zg = sigm(ac1[r] + bs1);
      float ng = tanh2(axn[r] + bi2 + rg*(ahn[r] + bh2));
      float hv = ng + zg*(hold[r] - ng);
      hold[r] = hv;
      store_s16_sc(orow + (size_t)r*H_, (uint32_t)f2bf(hv));
    }

    // ---- publish: per-wave tag after stores drain (no barrier) ----
    asm volatile("s_waitcnt vmcnt(0)" ::: "memory");
    if (lane == 0) store_u32_sc(towntag + wg*2 + mt, (uint32_t)(t + 1));
  }
}

__global__ void scores_kernel(const uint16_t* __restrict__ out2,
    const float* __restrict__ attn_w, const float* __restrict__ attn_b,
    const float* __restrict__ a1, float* __restrict__ scores)
{
  int gw = (blockIdx.x * blockDim.x + threadIdx.x) >> 6;
  int lane = threadIdx.x & 63;
  int b = gw >> 11, t = gw & 2047;
  float alpha = a1[0];
  u32x4 q = *(const u32x4*)(out2 + ((size_t)t*B_ + b)*H_ + lane*8);
  const uint16_t* ob = (const uint16_t*)&q;
  const float* aw = attn_w + lane*8;
  float acc = 0.f;
  #pragma unroll
  for (int i=0;i<8;++i){
    float ov = bf2f(ob[i]);
    ov = (ov >= 0.f) ? ov : alpha*ov;
    acc += ov * aw[i];
  }
  #pragma unroll
  for (int off=32; off>0; off>>=1) acc += __shfl_xor(acc, off, 64);
  if (lane == 0) scores[(size_t)b*T_ + t] = acc + attn_b[0];
}

__global__ void softmax_kernel(const float* __restrict__ scores, float* __restrict__ attn)
{
  int b = blockIdx.x, tid = threadIdx.x;
  __shared__ float red[256];
  const float* row = scores + (size_t)b*T_;
  float v[8]; float m = -3.4e38f;
  #pragma unroll
  for (int i=0;i<8;++i){ v[i] = row[tid + i*256]; m = fmaxf(m, v[i]); }
  red[tid] = m; __syncthreads();
  for (int s=128; s>0; s>>=1){ if (tid < s) red[tid] = fmaxf(red[tid], red[tid+s]); __syncthreads(); }
  m = red[0]; __syncthreads();
  float sum = 0.f;
  #pragma unroll
  for (int i=0;i<8;++i){ v[i] = __expf(v[i]-m); sum += v[i]; }
  red[tid] = sum; __syncthreads();
  for (int s=128; s>0; s>>=1){ if (tid < s) red[tid] += red[tid+s]; __syncthreads(); }
  float inv = 1.f / red[0];
  #pragma unroll
  for (int i=0;i<8;++i) attn[(size_t)b*T_ + tid + i*256] = v[i]*inv;
}

__global__ void final_kernel(const uint16_t* __restrict__ out2, const float* __restrict__ x,
    const float* __restrict__ attn, const float* __restrict__ dw, const float* __restrict__ db,
    const float* __restrict__ vw, const float* __restrict__ vb,
    const float* __restrict__ swt, const float* __restrict__ sb,
    const float* __restrict__ a1, float* __restrict__ dout)
{
  int gw = (blockIdx.x * blockDim.x + threadIdx.x) >> 6;
  int lane = threadIdx.x & 63;
  int b = gw >> 11, t = gw & 2047;
  float alpha = a1[0];
  u32x4 q = *(const u32x4*)(out2 + ((size_t)t*B_ + b)*H_ + lane*8);
  const uint16_t* ob = (const uint16_t*)&q;
  const float* xp = x + ((size_t)b*T_ + t)*12;
  float xr[12];
  #pragma unroll
  for (int i=0;i<12;++i) xr[i] = xp[i];
  float av = attn[(size_t)b*T_ + t];
  float acc[6] = {0,0,0,0,0,0};
  #pragma unroll
  for (int k=0;k<8;++k){
    int j = lane*8 + k;
    float ov = bf2f(ob[k]);
    ov = (ov >= 0.f) ? ov : alpha*ov;
    float d = db[j];
    const float* dwp = dw + (size_t)j*12;
    #pragma unroll
    for (int i=0;i<12;++i) d += xr[i]*dwp[i];
    float uo = ov + av*d;
    #pragma unroll
    for (int o=0;o<3;++o){
      acc[o]   += uo * vw[(size_t)o*H_ + j];
      acc[3+o] += uo * swt[(size_t)o*H_ + j];
    }
  }
  #pragma unroll
  for (int o=0;o<6;++o){
    #pragma unroll
    for (int off=32; off>0; off>>=1) acc[o] += __shfl_xor(acc[o], off, 64);
  }
  if (lane == 0){
    size_t p = ((size_t)b*T_ + t)*3;
    #pragma unroll
    for (int o=0;o<3;++o){
      dout[p + o] = acc[o] + vb[o];
      dout[(size_t)B_*T_*3 + p + o] = acc[3+o] + sb[o];
    }
  }
}

extern "C" void kernel_launch(void* const* d_in, const int* in_sizes, int n_in,
                              void* d_out, int out_size, void* d_ws, size_t ws_size,
                              hipStream_t stream)
{
  (void)in_sizes; (void)n_in; (void)out_size; (void)ws_size;
  const float* x        = (const float*)d_in[0];
  const float* vel_init = (const float*)d_in[1];
  const float* w_ih[3] = {(const float*)d_in[2], (const float*)d_in[6],  (const float*)d_in[10]};
  const float* w_hh[3] = {(const float*)d_in[3], (const float*)d_in[7],  (const float*)d_in[11]};
  const float* b_ih[3] = {(const float*)d_in[4], (const float*)d_in[8],  (const float*)d_in[12]};
  const float* b_hh[3] = {(const float*)d_in[5], (const float*)d_in[9],  (const float*)d_in[13]};
  const float* a1     = (const float*)d_in[14];
  const float* dec_w  = (const float*)d_in[15];
  const float* dec_b  = (const float*)d_in[16];
  const float* vd_w[3] = {(const float*)d_in[17], (const float*)d_in[19], (const float*)d_in[21]};
  const float* vd_b[3] = {(const float*)d_in[18], (const float*)d_in[20], (const float*)d_in[22]};
  const float* vel_w  = (const float*)d_in[23];
  const float* vel_b  = (const float*)d_in[24];
  const float* std_w  = (const float*)d_in[25];
  const float* std_b  = (const float*)d_in[26];
  const float* attn_w = (const float*)d_in[27];
  const float* attn_b = (const float*)d_in[28];

  char* ws = (char*)d_ws;                         // ~76.4 MB used
  uint16_t* out2   = (uint16_t*)(ws);                      // 64 MB
  uint16_t* ring0  = (uint16_t*)(ws + (size_t)67108864);   // 4 MB
  uint16_t* ring1  = (uint16_t*)(ws + (size_t)71303168);   // 4 MB
  float*    h0f    = (float*)   (ws + (size_t)75497472);   // 192 KB
  uint16_t* h0b    = (uint16_t*)(ws + (size_t)75694080);   // 96 KB
  float*    scores = (float*)   (ws + (size_t)75792384);   // 256 KB
  float*    attnp  = (float*)   (ws + (size_t)76054528);   // 256 KB
  uint32_t* tags   = (uint32_t*)(ws + (size_t)76316672);   // 768 B

  init_kernel<<<3, 256, 0, stream>>>(vel_init, vd_w[0], vd_b[0], vd_w[1], vd_b[1],
                                     vd_w[2], vd_b[2], h0f, h0b, tags);

  ScanParams P;
  P.x = x;
  for (int l=0;l<3;++l){ P.wih[l]=w_ih[l]; P.whh[l]=w_hh[l]; P.bih[l]=b_ih[l]; P.bhh[l]=b_hh[l]; }
  P.h0f = h0f; P.h0b = h0b;
  P.ring0 = ring0; P.ring1 = ring1; P.out2 = out2; P.tags = tags;

  fused_scan<<<96, 128, 0, stream>>>(P);

  scores_kernel<<<(B_*T_)/4, 256, 0, stream>>>(out2, attn_w, attn_b, a1, scores);
  softmax_kernel<<<B_, 256, 0, stream>>>(scores, attnp);
  final_kernel<<<(B_*T_)/4, 256, 0, stream>>>(out2, x, attnp, dec_w, dec_b,
                                              vel_w, vel_b, std_w, std_b, a1, (float*)d_out);
}

// Round 4
// 10444.332 us; speedup vs baseline: 1.7632x; 1.7632x over previous
//
#include <hip/hip_runtime.h>
#include <stdint.h>

// Fused 3-layer GRU pipeline: B=32, T=2048, I=12, H=512.
// 96 persistent WGs (32/layer, 16 hidden units each), 2 waves/WG (batch halves).
// SENTINEL PROTOCOL: h streams are bf16; 0xFFFF (NaN) is unreachable from
// finite gate math, so buffers are pre-poisoned to 0xFFFF and consumers
// validate "no element is sentinel" via packed-max. Element-wise monotonic
// (sentinel -> value, once) => no ordering assumptions, no tags, no drains.
// Producers re-poison their own slot region R/2 steps later, gated by a
// rarely-polled consumer progress counter. All cross-WG traffic sc0/sc1.

#define B_ 32
#define T_ 2048
#define H_ 512
#define R_ 128          // ring depth (steps); poison lag R_/2 = 64

typedef __attribute__((ext_vector_type(8))) short s8v;     // 8 bf16 (4 VGPR)
typedef __attribute__((ext_vector_type(4))) float f4v;     // MFMA acc
typedef __attribute__((ext_vector_type(4))) uint32_t u32x4;
typedef __attribute__((ext_vector_type(2))) unsigned short u16x2;

__device__ __forceinline__ uint16_t f2bf(float f){ return __builtin_bit_cast(uint16_t, (__bf16)f); }
__device__ __forceinline__ float bf2f(uint16_t b){ return __builtin_bit_cast(float, ((uint32_t)b)<<16); }

__device__ __forceinline__ s8v pack8(const float* f){
  s8v r;
  #pragma unroll
  for (int i=0;i<8;++i) r[i] = (short)f2bf(f[i]);
  return r;
}
__device__ __forceinline__ f4v mfma16(s8v a, s8v b, f4v c){
  return __builtin_amdgcn_mfma_f32_16x16x32_bf16(a,b,c,0,0,0);
}
#if __has_builtin(__builtin_amdgcn_rcpf)
__device__ __forceinline__ float rcp_(float x){ return __builtin_amdgcn_rcpf(x); }
#else
__device__ __forceinline__ float rcp_(float x){ return 1.0f/x; }
#endif
__device__ __forceinline__ float sigm(float s){ return rcp_(1.f + __expf(-s)); }
__device__ __forceinline__ float tanh2(float v){ return 1.f - 2.f*rcp_(1.f + __expf(2.f*v)); }

// device-coherent ops (bypass non-coherent per-XCD L2)
__device__ __forceinline__ u32x4 load_x4_sc(const void* p){
  u32x4 r;
  asm volatile("global_load_dwordx4 %0, %1, off sc0 sc1" : "=v"(r) : "v"(p) : "memory");
  return r;
}
__device__ __forceinline__ uint32_t load_u32_sc_wait(const void* p){
  uint32_t r;
  asm volatile("global_load_dword %0, %1, off sc0 sc1\n\ts_waitcnt vmcnt(0)"
               : "=v"(r) : "v"(p) : "memory");
  return r;
}
__device__ __forceinline__ void store_s16_sc(void* p, uint32_t v){
  asm volatile("global_store_short %0, %1, off sc0 sc1" :: "v"(p), "v"(v) : "memory");
}
__device__ __forceinline__ void store_u32_sc(void* p, uint32_t v){
  asm volatile("global_store_dword %0, %1, off sc0 sc1" :: "v"(p), "v"(v) : "memory");
}

// packed max over 16 chunks: result has any half == 0xFFFF iff any sentinel
__device__ __forceinline__ bool valid16(const u32x4* a){
  u16x2 m = {0, 0};
  #pragma unroll
  for (int c=0;c<16;++c){
    #pragma unroll
    for (int i=0;i<4;++i)
      m = __builtin_elementwise_max(m, __builtin_bit_cast(u16x2, a[c][i]));
  }
  unsigned short mm = (m[0] > m[1]) ? m[0] : m[1];
  return mm != (unsigned short)0xFFFFu;
}

__global__ void poison_kernel(uint32_t* p, unsigned int n16)
{
  u32x4 v = {0xFFFFFFFFu, 0xFFFFFFFFu, 0xFFFFFFFFu, 0xFFFFFFFFu};
  for (unsigned int k = blockIdx.x*blockDim.x + threadIdx.x; k < n16;
       k += gridDim.x*blockDim.x)
    ((u32x4*)p)[k] = v;
}

__global__ void init_kernel(const float* __restrict__ vel_init,
    const float* __restrict__ w0, const float* __restrict__ b0,
    const float* __restrict__ w1, const float* __restrict__ b1,
    const float* __restrict__ w2, const float* __restrict__ b2,
    float* __restrict__ h0f, uint16_t* __restrict__ h0b, uint32_t* progress)
{
  const int l = blockIdx.x, tid = threadIdx.x;
  const float* w  = (l==0)?w0:((l==1)?w1:w2);
  const float* bb = (l==0)?b0:((l==1)?b1:b2);
  for (int idx = tid; idx < B_*H_; idx += 256){
    int b = idx >> 9, j = idx & 511;
    float s = bb[j] + vel_init[b*3+0]*w[j*3+0] + vel_init[b*3+1]*w[j*3+1]
                    + vel_init[b*3+2]*w[j*3+2];
    h0f[(size_t)l*(B_*H_) + idx] = s;
    h0b[(size_t)l*(B_*H_) + idx] = f2bf(s);
  }
  if (l == 0 && tid < 192) progress[tid] = 0;   // 3 layers x 64 waves
}

struct ScanParams {
  const float* x;
  const float* wih[3];
  const float* whh[3];
  const float* bih[3];
  const float* bhh[3];
  const float* h0f;
  const uint16_t* h0b;
  uint16_t* ring0;   // [R_][B][H] bf16: layer0 out (h history + layer1 input)
  uint16_t* ring1;   // [R_][B][H] bf16: layer1 out
  uint16_t* out2;    // [T][B][H] bf16: layer2 out (h history + epilogue input)
  uint32_t* progress; // [3][64] per-wave completed steps (backpressure only)
};

__global__ __launch_bounds__(128, 1) void fused_scan(ScanParams P)
{
  const int tid  = threadIdx.x;
  const int lane = tid & 63;
  const int mt   = tid >> 6;            // wave = batch half (0/1)
  const int wgid = blockIdx.x;          // 0..95
  const int layer = wgid >> 5;          // 0..2
  const int wg   = wgid & 31;
  const int j0   = wg * 16;
  const int u    = lane & 15;           // unit col / A row
  const int lq   = lane >> 4;           // 0..3
  const int ko   = lq * 8;              // k octet (elements)
  const int bd   = lq * 4;              // D row base

  __shared__ uint16_t lds[48*512];      // wih slice (layers 1,2)

  const float* wih = P.wih[layer];
  const float* whh = P.whh[layer];
  const float* bih = P.bih[layer];
  const float* bhh = P.bhh[layer];

  const float bs0 = bih[0*H_ + j0 + u] + bhh[0*H_ + j0 + u];
  const float bs1 = bih[1*H_ + j0 + u] + bhh[1*H_ + j0 + u];
  const float bi2 = bih[2*H_ + j0 + u];
  const float bh2 = bhh[2*H_ + j0 + u];

  // W_hh B-fragments resident in VGPRs (48 frags = 192 VGPR/lane)
  s8v whhf[3][16];
  #pragma unroll
  for (int nt=0; nt<3; ++nt){
    #pragma unroll
    for (int ks=0; ks<16; ++ks){
      const float* wp = whh + (size_t)(nt*H_ + j0 + u)*H_ + ks*32 + ko;
      float tmp[8];
      #pragma unroll
      for (int i=0;i<8;++i) tmp[i] = wp[i];
      whhf[nt][ks] = pack8(tmp);
    }
  }

  s8v w0f[3];
  if (layer == 0){
    #pragma unroll
    for (int nt=0; nt<3; ++nt){
      float tmp[8];
      #pragma unroll
      for (int i=0;i<8;++i){
        int k = ko + i;
        tmp[i] = (k < 12) ? wih[(size_t)(nt*H_ + j0 + u)*12 + k] : 0.f;
      }
      w0f[nt] = pack8(tmp);
    }
  } else {
    // stage W_ih slice to LDS, bf16, XOR-swizzled (bit-5 term kills u/u+8 alias)
    for (int e = tid; e < (48*512)/8; e += 128) {
      int idx = e * 8;
      int g = idx >> 9, k = idx & 511;
      const float* wp = wih + (size_t)((g>>4)*H_ + j0 + (g&15))*H_ + k;
      float tmp[8];
      #pragma unroll
      for (int i=0;i<8;++i) tmp[i] = wp[i];
      s8v v = pack8(tmp);
      uint32_t msk = (uint32_t)((((g&7) ^ (((g>>3)&1)<<1))) << 4);
      uint32_t off = (uint32_t)g*1024u + ((((uint32_t)k)*2u) ^ msk);
      *(u32x4*)((char*)lds + off) = __builtin_bit_cast(u32x4, v);
    }
  }
  __syncthreads();

  const uint16_t* inring = (layer==1) ? P.ring0 : P.ring1;  // layer0 unused
  uint16_t* outbuf = (layer==0) ? P.ring0 : ((layer==1) ? P.ring1 : P.out2);
  const bool outlin = (layer == 2);
  uint32_t* myprog = P.progress + layer*64 + wg*2 + mt;
  const uint32_t* nextprog = (layer<2) ? (P.progress + (layer+1)*64) : nullptr;

  // fp32 hidden-state carry
  float hold[4];
  #pragma unroll
  for (int r=0;r<4;++r)
    hold[r] = P.h0f[(size_t)layer*(B_*H_) + (size_t)(mt*16 + bd + r)*H_ + j0 + u];

  const uint32_t sw  = (uint32_t)((((u&7) ^ (((u>>3)&1)<<1))) << 4);
  const uint32_t gb0 = (uint32_t)((0*16 + u) * 1024);
  const uint32_t gb1 = (uint32_t)((1*16 + u) * 1024);
  const uint32_t gb2 = (uint32_t)((2*16 + u) * 1024);
  const uint32_t koB = (uint32_t)(ko * 2);

  int poison_until = R_/2 + 60;   // t <= this may poison without polling

  for (int t = 0; t < T_; ++t) {
    f4v ac0 = {0,0,0,0}, ac1 = {0,0,0,0}, axn = {0,0,0,0}, ahn = {0,0,0,0};

    // ---- layer-0 x-part: off the critical path ----
    if (layer == 0) {
      const float* xp = P.x + ((size_t)(mt*16 + u)*T_ + (size_t)t)*12;
      float4 lo  = *(const float4*)(xp);
      float4 md  = *(const float4*)(xp + 4);
      float4 hi4 = *(const float4*)(xp + 8);
      float xv[8];
      xv[0] = (ko==0) ? lo.x : hi4.x;  xv[1] = (ko==0) ? lo.y : hi4.y;
      xv[2] = (ko==0) ? lo.z : hi4.z;  xv[3] = (ko==0) ? lo.w : hi4.w;
      xv[4] = (ko==0) ? md.x : 0.f;    xv[5] = (ko==0) ? md.y : 0.f;
      xv[6] = (ko==0) ? md.z : 0.f;    xv[7] = (ko==0) ? md.w : 0.f;
      s8v a = pack8(xv);
      ac0 = mfma16(a, w0f[0], ac0);
      ac1 = mfma16(a, w0f[1], ac1);
      axn = mfma16(a, w0f[2], axn);
    }

    // ---- poison duty (layers 0,1): re-sentinel slot rewritten at t+R/2 ----
    if (layer < 2 && t >= R_/2) {
      if (t > poison_until) {
        // poll next-layer progress; grant window poison_until = min + R/2 - 4
        while (1) {
          int c = (int)load_u32_sc_wait(nextprog + lane);
          #pragma unroll
          for (int off=32; off>0; off>>=1){
            int c2 = __shfl_xor(c, off, 64);
            c = (c2 < c) ? c2 : c;
          }
          poison_until = c + R_/2 - 4;
          if (t <= poison_until) break;
          __builtin_amdgcn_s_sleep(8);
        }
      }
      int sp = (t + R_/2) & (R_-1);
      uint16_t* prow = outbuf + (size_t)sp*(B_*H_) + (size_t)(mt*16 + bd)*H_ + j0 + u;
      #pragma unroll
      for (int r=0;r<4;++r) store_s16_sc(prow + (size_t)r*H_, 0xFFFFu);
    }

    // ---- publish progress (backpressure only; every 16 steps) ----
    if (layer > 0 && (t & 15) == 15 && lane == 0)
      store_u32_sc(myprog, (uint32_t)t);     // conservative: completed >= t-1

    // ---- speculative issue of h + x, validate (sentinel protocol) ----
    u32x4 xa[16], ha[16];
    bool xok = (layer == 0);
    bool hok = (t == 0);
    const uint16_t* hp = ((t == 0)
        ? (P.h0b + (size_t)layer*(B_*H_))
        : (outlin ? (P.out2 + (size_t)(t-1)*(B_*H_))
                  : (outbuf + (size_t)((t-1) & (R_-1))*(B_*H_))))
        + (size_t)(mt*16+u)*H_ + ko;
    const uint16_t* xin = (layer > 0)
        ? (inring + (size_t)(t & (R_-1))*(B_*H_) + (size_t)(mt*16+u)*H_ + ko)
        : nullptr;

    #pragma unroll
    for (int ks=0; ks<16; ++ks) ha[ks] = load_x4_sc(hp + ks*32);
    if (layer > 0) {
      #pragma unroll
      for (int ks=0; ks<16; ++ks) xa[ks] = load_x4_sc(xin + ks*32);
    }
    asm volatile("s_waitcnt vmcnt(0)" ::: "memory");
    __builtin_amdgcn_sched_barrier(0);
    if (!hok) hok = (__ballot(valid16(ha)) == ~0ull);
    if (!xok) xok = (__ballot(valid16(xa)) == ~0ull);

    // respin x (reloading h too if it was stale)
    while (!xok) {
      #pragma unroll
      for (int ks=0; ks<16; ++ks) xa[ks] = load_x4_sc(xin + ks*32);
      if (!hok) {
        #pragma unroll
        for (int ks=0; ks<16; ++ks) ha[ks] = load_x4_sc(hp + ks*32);
      }
      asm volatile("s_waitcnt vmcnt(0)" ::: "memory");
      __builtin_amdgcn_sched_barrier(0);
      xok = (__ballot(valid16(xa)) == ~0ull);
      if (!hok) hok = (__ballot(valid16(ha)) == ~0ull);
    }

    // ---- x-part MFMAs (layers 1,2) — run during h propagation window ----
    if (layer > 0) {
      #pragma unroll
      for (int ks=0; ks<16; ++ks){
        s8v a = __builtin_bit_cast(s8v, xa[ks]);
        uint32_t kk = ((uint32_t)(ks*64) + koB) ^ sw;
        s8v w0 = *(const s8v*)((const char*)lds + gb0 + kk);
        s8v w1 = *(const s8v*)((const char*)lds + gb1 + kk);
        s8v w2 = *(const s8v*)((const char*)lds + gb2 + kk);
        ac0 = mfma16(a, w0, ac0);
        ac1 = mfma16(a, w1, ac1);
        axn = mfma16(a, w2, axn);
      }
    }

    // ---- h spin ----
    while (!hok) {
      #pragma unroll
      for (int ks=0; ks<16; ++ks) ha[ks] = load_x4_sc(hp + ks*32);
      asm volatile("s_waitcnt vmcnt(0)" ::: "memory");
      __builtin_amdgcn_sched_barrier(0);
      hok = (__ballot(valid16(ha)) == ~0ull);
    }

    // ---- h-part MFMAs ----
    #pragma unroll
    for (int ks=0; ks<16; ++ks){
      s8v a = __builtin_bit_cast(s8v, ha[ks]);
      ac0 = mfma16(a, whhf[0][ks], ac0);
      ac1 = mfma16(a, whhf[1][ks], ac1);
      ahn = mfma16(a, whhf[2][ks], ahn);
    }

    // ---- gates + stores (no drain, no publish) ----
    uint16_t* orow = outbuf
        + (outlin ? (size_t)t*(B_*H_) : (size_t)(t & (R_-1))*(B_*H_))
        + (size_t)(mt*16 + bd)*H_ + j0 + u;
    #pragma unroll
    for (int r=0;r<4;++r){
      float rg = sigm(ac0[r] + bs0);
      float zg = sigm(ac1[r] + bs1);
      float ng = tanh2(axn[r] + bi2 + rg*(ahn[r] + bh2));
      float hv = ng + zg*(hold[r] - ng);
      hold[r] = hv;
      store_s16_sc(orow + (size_t)r*H_, (uint32_t)f2bf(hv));
    }
  }
}

__global__ void scores_kernel(const uint16_t* __restrict__ out2,
    const float* __restrict__ attn_w, const float* __restrict__ attn_b,
    const float* __restrict__ a1, float* __restrict__ scores)
{
  int gw = (blockIdx.x * blockDim.x + threadIdx.x) >> 6;
  int lane = threadIdx.x & 63;
  int b = gw >> 11, t = gw & 2047;
  float alpha = a1[0];
  u32x4 q = *(const u32x4*)(out2 + ((size_t)t*B_ + b)*H_ + lane*8);
  const uint16_t* ob = (const uint16_t*)&q;
  const float* aw = attn_w + lane*8;
  float acc = 0.f;
  #pragma unroll
  for (int i=0;i<8;++i){
    float ov = bf2f(ob[i]);
    ov = (ov >= 0.f) ? ov : alpha*ov;
    acc += ov * aw[i];
  }
  #pragma unroll
  for (int off=32; off>0; off>>=1) acc += __shfl_xor(acc, off, 64);
  if (lane == 0) scores[(size_t)b*T_ + t] = acc + attn_b[0];
}

__global__ void softmax_kernel(const float* __restrict__ scores, float* __restrict__ attn)
{
  int b = blockIdx.x, tid = threadIdx.x;
  __shared__ float red[256];
  const float* row = scores + (size_t)b*T_;
  float v[8]; float m = -3.4e38f;
  #pragma unroll
  for (int i=0;i<8;++i){ v[i] = row[tid + i*256]; m = fmaxf(m, v[i]); }
  red[tid] = m; __syncthreads();
  for (int s=128; s>0; s>>=1){ if (tid < s) red[tid] = fmaxf(red[tid], red[tid+s]); __syncthreads(); }
  m = red[0]; __syncthreads();
  float sum = 0.f;
  #pragma unroll
  for (int i=0;i<8;++i){ v[i] = __expf(v[i]-m); sum += v[i]; }
  red[tid] = sum; __syncthreads();
  for (int s=128; s>0; s>>=1){ if (tid < s) red[tid] += red[tid+s]; __syncthreads(); }
  float inv = 1.f / red[0];
  #pragma unroll
  for (int i=0;i<8;++i) attn[(size_t)b*T_ + tid + i*256] = v[i]*inv;
}

__global__ void final_kernel(const uint16_t* __restrict__ out2, const float* __restrict__ x,
    const float* __restrict__ attn, const float* __restrict__ dw, const float* __restrict__ db,
    const float* __restrict__ vw, const float* __restrict__ vb,
    const float* __restrict__ swt, const float* __restrict__ sb,
    const float* __restrict__ a1, float* __restrict__ dout)
{
  int gw = (blockIdx.x * blockDim.x + threadIdx.x) >> 6;
  int lane = threadIdx.x & 63;
  int b = gw >> 11, t = gw & 2047;
  float alpha = a1[0];
  u32x4 q = *(const u32x4*)(out2 + ((size_t)t*B_ + b)*H_ + lane*8);
  const uint16_t* ob = (const uint16_t*)&q;
  const float* xp = x + ((size_t)b*T_ + t)*12;
  float xr[12];
  #pragma unroll
  for (int i=0;i<12;++i) xr[i] = xp[i];
  float av = attn[(size_t)b*T_ + t];
  float acc[6] = {0,0,0,0,0,0};
  #pragma unroll
  for (int k=0;k<8;++k){
    int j = lane*8 + k;
    float ov = bf2f(ob[k]);
    ov = (ov >= 0.f) ? ov : alpha*ov;
    float d = db[j];
    const float* dwp = dw + (size_t)j*12;
    #pragma unroll
    for (int i=0;i<12;++i) d += xr[i]*dwp[i];
    float uo = ov + av*d;
    #pragma unroll
    for (int o=0;o<3;++o){
      acc[o]   += uo * vw[(size_t)o*H_ + j];
      acc[3+o] += uo * swt[(size_t)o*H_ + j];
    }
  }
  #pragma unroll
  for (int o=0;o<6;++o){
    #pragma unroll
    for (int off=32; off>0; off>>=1) acc[o] += __shfl_xor(acc[o], off, 64);
  }
  if (lane == 0){
    size_t p = ((size_t)b*T_ + t)*3;
    #pragma unroll
    for (int o=0;o<3;++o){
      dout[p + o] = acc[o] + vb[o];
      dout[(size_t)B_*T_*3 + p + o] = acc[3+o] + sb[o];
    }
  }
}

extern "C" void kernel_launch(void* const* d_in, const int* in_sizes, int n_in,
                              void* d_out, int out_size, void* d_ws, size_t ws_size,
                              hipStream_t stream)
{
  (void)in_sizes; (void)n_in; (void)out_size; (void)ws_size;
  const float* x        = (const float*)d_in[0];
  const float* vel_init = (const float*)d_in[1];
  const float* w_ih[3] = {(const float*)d_in[2], (const float*)d_in[6],  (const float*)d_in[10]};
  const float* w_hh[3] = {(const float*)d_in[3], (const float*)d_in[7],  (const float*)d_in[11]};
  const float* b_ih[3] = {(const float*)d_in[4], (const float*)d_in[8],  (const float*)d_in[12]};
  const float* b_hh[3] = {(const float*)d_in[5], (const float*)d_in[9],  (const float*)d_in[13]};
  const float* a1     = (const float*)d_in[14];
  const float* dec_w  = (const float*)d_in[15];
  const float* dec_b  = (const float*)d_in[16];
  const float* vd_w[3] = {(const float*)d_in[17], (const float*)d_in[19], (const float*)d_in[21]};
  const float* vd_b[3] = {(const float*)d_in[18], (const float*)d_in[20], (const float*)d_in[22]};
  const float* vel_w  = (const float*)d_in[23];
  const float* vel_b  = (const float*)d_in[24];
  const float* std_w  = (const float*)d_in[25];
  const float* std_b  = (const float*)d_in[26];
  const float* attn_w = (const float*)d_in[27];
  const float* attn_b = (const float*)d_in[28];

  char* ws = (char*)d_ws;                         // ~76.4 MB used
  uint16_t* out2   = (uint16_t*)(ws);                      // 64 MB
  uint16_t* ring0  = (uint16_t*)(ws + (size_t)67108864);   // 4 MB
  uint16_t* ring1  = (uint16_t*)(ws + (size_t)71303168);   // 4 MB
  float*    h0f    = (float*)   (ws + (size_t)75497472);   // 192 KB
  uint16_t* h0b    = (uint16_t*)(ws + (size_t)75694080);   // 96 KB
  float*    scores = (float*)   (ws + (size_t)75792384);   // 256 KB
  float*    attnp  = (float*)   (ws + (size_t)76054528);   // 256 KB
  uint32_t* progress = (uint32_t*)(ws + (size_t)76316672); // 768 B

  // sentinel-poison out2 + both rings (contiguous 72 MB), every call
  poison_kernel<<<2048, 256, 0, stream>>>((uint32_t*)ws, 72u*1024u*1024u/16u);
  init_kernel<<<3, 256, 0, stream>>>(vel_init, vd_w[0], vd_b[0], vd_w[1], vd_b[1],
                                     vd_w[2], vd_b[2], h0f, h0b, progress);

  ScanParams P;
  P.x = x;
  for (int l=0;l<3;++l){ P.wih[l]=w_ih[l]; P.whh[l]=w_hh[l]; P.bih[l]=b_ih[l]; P.bhh[l]=b_hh[l]; }
  P.h0f = h0f; P.h0b = h0b;
  P.ring0 = ring0; P.ring1 = ring1; P.out2 = out2; P.progress = progress;

  fused_scan<<<96, 128, 0, stream>>>(P);

  scores_kernel<<<(B_*T_)/4, 256, 0, stream>>>(out2, attn_w, attn_b, a1, scores);
  softmax_kernel<<<B_, 256, 0, stream>>>(scores, attnp);
  final_kernel<<<(B_*T_)/4, 256, 0, stream>>>(out2, x, attnp, dec_w, dec_b,
                                              vel_w, vel_b, std_w, std_b, a1, (float*)d_out);
}

// Round 5
// 8427.074 us; speedup vs baseline: 2.1852x; 1.2394x over previous
//
#include <hip/hip_runtime.h>
#include <stdint.h>

// Fused 3-layer GRU pipeline: B=32, T=2048, I=12, H=512.
// 96 persistent WGs (32/layer, 16 hidden units each), 2 waves/WG (batch halves).
// SENTINEL PROTOCOL: bf16 0xFFFF is unreachable from finite gate math; buffers
// pre-poisoned to 0xFFFF; consumers validate elements. Element-wise monotonic
// => no ordering assumptions, no tags, no store drains.
// R5: canary backoff (512B spin instead of 16KB re-load), x-phase before
// h-phase (lag-1 x nearly always ready; h gets extra slack), poison after
// stores, safe initial poison window.

#define B_ 32
#define T_ 2048
#define H_ 512
#define R_ 128          // ring depth (steps); poison lag R_/2 = 64

typedef __attribute__((ext_vector_type(8))) short s8v;     // 8 bf16 (4 VGPR)
typedef __attribute__((ext_vector_type(4))) float f4v;     // MFMA acc
typedef __attribute__((ext_vector_type(4))) uint32_t u32x4;
typedef __attribute__((ext_vector_type(2))) unsigned short u16x2;

__device__ __forceinline__ uint16_t f2bf(float f){ return __builtin_bit_cast(uint16_t, (__bf16)f); }
__device__ __forceinline__ float bf2f(uint16_t b){ return __builtin_bit_cast(float, ((uint32_t)b)<<16); }

__device__ __forceinline__ s8v pack8(const float* f){
  s8v r;
  #pragma unroll
  for (int i=0;i<8;++i) r[i] = (short)f2bf(f[i]);
  return r;
}
__device__ __forceinline__ f4v mfma16(s8v a, s8v b, f4v c){
  return __builtin_amdgcn_mfma_f32_16x16x32_bf16(a,b,c,0,0,0);
}
#if __has_builtin(__builtin_amdgcn_rcpf)
__device__ __forceinline__ float rcp_(float x){ return __builtin_amdgcn_rcpf(x); }
#else
__device__ __forceinline__ float rcp_(float x){ return 1.0f/x; }
#endif
__device__ __forceinline__ float sigm(float s){ return rcp_(1.f + __expf(-s)); }
__device__ __forceinline__ float tanh2(float v){ return 1.f - 2.f*rcp_(1.f + __expf(2.f*v)); }

// device-coherent ops (bypass non-coherent per-XCD L2)
__device__ __forceinline__ u32x4 load_x4_sc(const void* p){
  u32x4 r;
  asm volatile("global_load_dwordx4 %0, %1, off sc0 sc1" : "=v"(r) : "v"(p) : "memory");
  return r;
}
// load + wait fused in one asm block: consumer of the result is ordered after
// the waitcnt by the register data dependency (rule-#18 safe)
__device__ __forceinline__ u32x4 load_x4_sc_wait(const void* p){
  u32x4 r;
  asm volatile("global_load_dwordx4 %0, %1, off sc0 sc1\n\ts_waitcnt vmcnt(0)"
               : "=v"(r) : "v"(p) : "memory");
  return r;
}
__device__ __forceinline__ uint32_t load_u32_sc_wait(const void* p){
  uint32_t r;
  asm volatile("global_load_dword %0, %1, off sc0 sc1\n\ts_waitcnt vmcnt(0)"
               : "=v"(r) : "v"(p) : "memory");
  return r;
}
__device__ __forceinline__ void store_s16_sc(void* p, uint32_t v){
  asm volatile("global_store_short %0, %1, off sc0 sc1" :: "v"(p), "v"(v) : "memory");
}
__device__ __forceinline__ void store_u32_sc(void* p, uint32_t v){
  asm volatile("global_store_dword %0, %1, off sc0 sc1" :: "v"(p), "v"(v) : "memory");
}

__device__ __forceinline__ bool chunk_ok(u32x4 c){
  u16x2 m = __builtin_bit_cast(u16x2, c[0]);
  m = __builtin_elementwise_max(m, __builtin_bit_cast(u16x2, c[1]));
  m = __builtin_elementwise_max(m, __builtin_bit_cast(u16x2, c[2]));
  m = __builtin_elementwise_max(m, __builtin_bit_cast(u16x2, c[3]));
  unsigned short mm = (m[0] > m[1]) ? m[0] : m[1];
  return mm != (unsigned short)0xFFFFu;
}
// all 16 chunks sentinel-free?
__device__ __forceinline__ bool valid16(const u32x4* a){
  u16x2 m = {0, 0};
  #pragma unroll
  for (int c=0;c<16;++c){
    #pragma unroll
    for (int i=0;i<4;++i)
      m = __builtin_elementwise_max(m, __builtin_bit_cast(u16x2, a[c][i]));
  }
  unsigned short mm = (m[0] > m[1]) ? m[0] : m[1];
  return mm != (unsigned short)0xFFFFu;
}

__global__ void poison_kernel(uint32_t* p, unsigned int n16)
{
  u32x4 v = {0xFFFFFFFFu, 0xFFFFFFFFu, 0xFFFFFFFFu, 0xFFFFFFFFu};
  for (unsigned int k = blockIdx.x*blockDim.x + threadIdx.x; k < n16;
       k += gridDim.x*blockDim.x)
    ((u32x4*)p)[k] = v;
}

__global__ void init_kernel(const float* __restrict__ vel_init,
    const float* __restrict__ w0, const float* __restrict__ b0,
    const float* __restrict__ w1, const float* __restrict__ b1,
    const float* __restrict__ w2, const float* __restrict__ b2,
    float* __restrict__ h0f, uint16_t* __restrict__ h0b, uint32_t* progress)
{
  const int l = blockIdx.x, tid = threadIdx.x;
  const float* w  = (l==0)?w0:((l==1)?w1:w2);
  const float* bb = (l==0)?b0:((l==1)?b1:b2);
  for (int idx = tid; idx < B_*H_; idx += 256){
    int b = idx >> 9, j = idx & 511;
    float s = bb[j] + vel_init[b*3+0]*w[j*3+0] + vel_init[b*3+1]*w[j*3+1]
                    + vel_init[b*3+2]*w[j*3+2];
    h0f[(size_t)l*(B_*H_) + idx] = s;
    h0b[(size_t)l*(B_*H_) + idx] = f2bf(s);
  }
  if (l == 0 && tid < 192) progress[tid] = 0;   // 3 layers x 64 waves
}

struct ScanParams {
  const float* x;
  const float* wih[3];
  const float* whh[3];
  const float* bih[3];
  const float* bhh[3];
  const float* h0f;
  const uint16_t* h0b;
  uint16_t* ring0;   // [R_][B][H] bf16: layer0 out
  uint16_t* ring1;   // [R_][B][H] bf16: layer1 out
  uint16_t* out2;    // [T][B][H] bf16: layer2 out (h history + epilogue input)
  uint32_t* progress; // [3][64] per-wave completed steps (backpressure only)
};

__global__ __launch_bounds__(128, 1) void fused_scan(ScanParams P)
{
  const int tid  = threadIdx.x;
  const int lane = tid & 63;
  const int mt   = tid >> 6;            // wave = batch half (0/1)
  const int wgid = blockIdx.x;          // 0..95
  const int layer = wgid >> 5;          // 0..2
  const int wg   = wgid & 31;
  const int j0   = wg * 16;
  const int u    = lane & 15;           // unit col / A row
  const int lq   = lane >> 4;           // 0..3
  const int ko   = lq * 8;              // k octet (elements)
  const int bd   = lq * 4;              // D row base

  __shared__ uint16_t lds[48*512];      // wih slice (layers 1,2)

  const float* wih = P.wih[layer];
  const float* whh = P.whh[layer];
  const float* bih = P.bih[layer];
  const float* bhh = P.bhh[layer];

  const float bs0 = bih[0*H_ + j0 + u] + bhh[0*H_ + j0 + u];
  const float bs1 = bih[1*H_ + j0 + u] + bhh[1*H_ + j0 + u];
  const float bi2 = bih[2*H_ + j0 + u];
  const float bh2 = bhh[2*H_ + j0 + u];

  // W_hh B-fragments resident in VGPRs (48 frags = 192 VGPR/lane)
  s8v whhf[3][16];
  #pragma unroll
  for (int nt=0; nt<3; ++nt){
    #pragma unroll
    for (int ks=0; ks<16; ++ks){
      const float* wp = whh + (size_t)(nt*H_ + j0 + u)*H_ + ks*32 + ko;
      float tmp[8];
      #pragma unroll
      for (int i=0;i<8;++i) tmp[i] = wp[i];
      whhf[nt][ks] = pack8(tmp);
    }
  }

  s8v w0f[3];
  if (layer == 0){
    #pragma unroll
    for (int nt=0; nt<3; ++nt){
      float tmp[8];
      #pragma unroll
      for (int i=0;i<8;++i){
        int k = ko + i;
        tmp[i] = (k < 12) ? wih[(size_t)(nt*H_ + j0 + u)*12 + k] : 0.f;
      }
      w0f[nt] = pack8(tmp);
    }
  } else {
    // stage W_ih slice to LDS, bf16, XOR-swizzled (bit-5 term kills u/u+8 alias)
    for (int e = tid; e < (48*512)/8; e += 128) {
      int idx = e * 8;
      int g = idx >> 9, k = idx & 511;
      const float* wp = wih + (size_t)((g>>4)*H_ + j0 + (g&15))*H_ + k;
      float tmp[8];
      #pragma unroll
      for (int i=0;i<8;++i) tmp[i] = wp[i];
      s8v v = pack8(tmp);
      uint32_t msk = (uint32_t)((((g&7) ^ (((g>>3)&1)<<1))) << 4);
      uint32_t off = (uint32_t)g*1024u + ((((uint32_t)k)*2u) ^ msk);
      *(u32x4*)((char*)lds + off) = __builtin_bit_cast(u32x4, v);
    }
  }
  __syncthreads();

  const uint16_t* inring = (layer==1) ? P.ring0 : P.ring1;  // layer0 unused
  uint16_t* outbuf = (layer==0) ? P.ring0 : ((layer==1) ? P.ring1 : P.out2);
  const bool outlin = (layer == 2);
  uint32_t* myprog = P.progress + layer*64 + wg*2 + mt;
  const uint32_t* nextprog = (layer<2) ? (P.progress + (layer+1)*64) : nullptr;

  // fp32 hidden-state carry
  float hold[4];
  #pragma unroll
  for (int r=0;r<4;++r)
    hold[r] = P.h0f[(size_t)layer*(B_*H_) + (size_t)(mt*16 + bd + r)*H_ + j0 + u];

  const uint32_t sw  = (uint32_t)((((u&7) ^ (((u>>3)&1)<<1))) << 4);
  const uint32_t gb0 = (uint32_t)((0*16 + u) * 1024);
  const uint32_t gb1 = (uint32_t)((1*16 + u) * 1024);
  const uint32_t gb2 = (uint32_t)((2*16 + u) * 1024);
  const uint32_t koB = (uint32_t)(ko * 2);
  const int cl = lane & 31;             // canary producer index

  int poison_until = R_/2 - 4;   // t <= this may poison without polling (safe:
                                 // only initial-garbage slots are touched)

  for (int t = 0; t < T_; ++t) {
    f4v ac0 = {0,0,0,0}, ac1 = {0,0,0,0}, axn = {0,0,0,0}, ahn = {0,0,0,0};

    // ================= PHASE X =================
    if (layer == 0) {
      const float* xp = P.x + ((size_t)(mt*16 + u)*T_ + (size_t)t)*12;
      float4 lo  = *(const float4*)(xp);
      float4 md  = *(const float4*)(xp + 4);
      float4 hi4 = *(const float4*)(xp + 8);
      float xv[8];
      xv[0] = (ko==0) ? lo.x : hi4.x;  xv[1] = (ko==0) ? lo.y : hi4.y;
      xv[2] = (ko==0) ? lo.z : hi4.z;  xv[3] = (ko==0) ? lo.w : hi4.w;
      xv[4] = (ko==0) ? md.x : 0.f;    xv[5] = (ko==0) ? md.y : 0.f;
      xv[6] = (ko==0) ? md.z : 0.f;    xv[7] = (ko==0) ? md.w : 0.f;
      s8v a = pack8(xv);
      ac0 = mfma16(a, w0f[0], ac0);
      ac1 = mfma16(a, w0f[1], ac1);
      axn = mfma16(a, w0f[2], axn);
    } else {
      const uint16_t* xslot = inring + (size_t)(t & (R_-1))*(B_*H_);
      const uint16_t* xin  = xslot + (size_t)(mt*16+u)*H_ + ko;
      const uint16_t* xcan = xslot + (size_t)(mt*16)*H_ + cl*16;
      u32x4 xa[16];
      while (1) {
        #pragma unroll
        for (int ks=0; ks<16; ++ks) xa[ks] = load_x4_sc(xin + ks*32);
        asm volatile("s_waitcnt vmcnt(0)" ::: "memory");
        __builtin_amdgcn_sched_barrier(0);
        if (__ballot(valid16(xa)) == ~0ull) break;
        while (1) {                       // cheap canary spin (512 B / iter)
          u32x4 c = load_x4_sc_wait(xcan);
          if (__ballot(chunk_ok(c)) == ~0ull) break;
          __builtin_amdgcn_s_sleep(2);
        }
      }
      #pragma unroll
      for (int ks=0; ks<16; ++ks){
        s8v a = __builtin_bit_cast(s8v, xa[ks]);
        uint32_t kk = ((uint32_t)(ks*64) + koB) ^ sw;
        s8v w0 = *(const s8v*)((const char*)lds + gb0 + kk);
        s8v w1 = *(const s8v*)((const char*)lds + gb1 + kk);
        s8v w2 = *(const s8v*)((const char*)lds + gb2 + kk);
        ac0 = mfma16(a, w0, ac0);
        ac1 = mfma16(a, w1, ac1);
        axn = mfma16(a, w2, axn);
      }
    }

    // ================= PHASE H =================
    const uint16_t* hslot = (t == 0)
        ? (P.h0b + (size_t)layer*(B_*H_))
        : (outlin ? (P.out2 + (size_t)(t-1)*(B_*H_))
                  : (outbuf + (size_t)((t-1) & (R_-1))*(B_*H_)));
    const uint16_t* hp   = hslot + (size_t)(mt*16+u)*H_ + ko;
    const uint16_t* hcan = hslot + (size_t)(mt*16)*H_ + cl*16;
    u32x4 ha[16];
    while (1) {
      #pragma unroll
      for (int ks=0; ks<16; ++ks) ha[ks] = load_x4_sc(hp + ks*32);
      asm volatile("s_waitcnt vmcnt(0)" ::: "memory");
      __builtin_amdgcn_sched_barrier(0);
      if (t == 0) break;
      if (__ballot(valid16(ha)) == ~0ull) break;
      while (1) {                         // cheap canary spin
        u32x4 c = load_x4_sc_wait(hcan);
        if (__ballot(chunk_ok(c)) == ~0ull) break;
        __builtin_amdgcn_s_sleep(2);
      }
    }
    #pragma unroll
    for (int ks=0; ks<16; ++ks){
      s8v a = __builtin_bit_cast(s8v, ha[ks]);
      ac0 = mfma16(a, whhf[0][ks], ac0);
      ac1 = mfma16(a, whhf[1][ks], ac1);
      ahn = mfma16(a, whhf[2][ks], ahn);
    }

    // ================= GATES + STORES =================
    uint16_t* orow = outbuf
        + (outlin ? (size_t)t*(B_*H_) : (size_t)(t & (R_-1))*(B_*H_))
        + (size_t)(mt*16 + bd)*H_ + j0 + u;
    #pragma unroll
    for (int r=0;r<4;++r){
      float rg = sigm(ac0[r] + bs0);
      float zg = sigm(ac1[r] + bs1);
      float ng = tanh2(axn[r] + bi2 + rg*(ahn[r] + bh2));
      float hv = ng + zg*(hold[r] - ng);
      hold[r] = hv;
      store_s16_sc(orow + (size_t)r*H_, (uint32_t)f2bf(hv));
    }

    // ---- progress publish (backpressure only; every 16 steps) ----
    if (layer > 0 && (t & 15) == 15 && lane == 0)
      store_u32_sc(myprog, (uint32_t)t);       // "completed step t"

    // ---- poison duty (layers 0,1): re-sentinel slot for step t+R/2 ----
    if (layer < 2 && t >= R_/2) {
      if (t > poison_until) {
        while (1) {
          int c = (int)load_u32_sc_wait(nextprog + lane);
          #pragma unroll
          for (int off=32; off>0; off>>=1){
            int c2 = __shfl_xor(c, off, 64);
            c = (c2 < c) ? c2 : c;
          }
          poison_until = c + R_/2 - 4;
          if (t <= poison_until) break;
          __builtin_amdgcn_s_sleep(8);
        }
      }
      int sp = (t + R_/2) & (R_-1);
      uint16_t* prow = outbuf + (size_t)sp*(B_*H_) + (size_t)(mt*16 + bd)*H_ + j0 + u;
      #pragma unroll
      for (int r=0;r<4;++r) store_s16_sc(prow + (size_t)r*H_, 0xFFFFu);
    }
  }
}

__global__ void scores_kernel(const uint16_t* __restrict__ out2,
    const float* __restrict__ attn_w, const float* __restrict__ attn_b,
    const float* __restrict__ a1, float* __restrict__ scores)
{
  int gw = (blockIdx.x * blockDim.x + threadIdx.x) >> 6;
  int lane = threadIdx.x & 63;
  int b = gw >> 11, t = gw & 2047;
  float alpha = a1[0];
  u32x4 q = *(const u32x4*)(out2 + ((size_t)t*B_ + b)*H_ + lane*8);
  const uint16_t* ob = (const uint16_t*)&q;
  const float* aw = attn_w + lane*8;
  float acc = 0.f;
  #pragma unroll
  for (int i=0;i<8;++i){
    float ov = bf2f(ob[i]);
    ov = (ov >= 0.f) ? ov : alpha*ov;
    acc += ov * aw[i];
  }
  #pragma unroll
  for (int off=32; off>0; off>>=1) acc += __shfl_xor(acc, off, 64);
  if (lane == 0) scores[(size_t)b*T_ + t] = acc + attn_b[0];
}

__global__ void softmax_kernel(const float* __restrict__ scores, float* __restrict__ attn)
{
  int b = blockIdx.x, tid = threadIdx.x;
  __shared__ float red[256];
  const float* row = scores + (size_t)b*T_;
  float v[8]; float m = -3.4e38f;
  #pragma unroll
  for (int i=0;i<8;++i){ v[i] = row[tid + i*256]; m = fmaxf(m, v[i]); }
  red[tid] = m; __syncthreads();
  for (int s=128; s>0; s>>=1){ if (tid < s) red[tid] = fmaxf(red[tid], red[tid+s]); __syncthreads(); }
  m = red[0]; __syncthreads();
  float sum = 0.f;
  #pragma unroll
  for (int i=0;i<8;++i){ v[i] = __expf(v[i]-m); sum += v[i]; }
  red[tid] = sum; __syncthreads();
  for (int s=128; s>0; s>>=1){ if (tid < s) red[tid] += red[tid+s]; __syncthreads(); }
  float inv = 1.f / red[0];
  #pragma unroll
  for (int i=0;i<8;++i) attn[(size_t)b*T_ + tid + i*256] = v[i]*inv;
}

__global__ void final_kernel(const uint16_t* __restrict__ out2, const float* __restrict__ x,
    const float* __restrict__ attn, const float* __restrict__ dw, const float* __restrict__ db,
    const float* __restrict__ vw, const float* __restrict__ vb,
    const float* __restrict__ swt, const float* __restrict__ sb,
    const float* __restrict__ a1, float* __restrict__ dout)
{
  int gw = (blockIdx.x * blockDim.x + threadIdx.x) >> 6;
  int lane = threadIdx.x & 63;
  int b = gw >> 11, t = gw & 2047;
  float alpha = a1[0];
  u32x4 q = *(const u32x4*)(out2 + ((size_t)t*B_ + b)*H_ + lane*8);
  const uint16_t* ob = (const uint16_t*)&q;
  const float* xp = x + ((size_t)b*T_ + t)*12;
  float xr[12];
  #pragma unroll
  for (int i=0;i<12;++i) xr[i] = xp[i];
  float av = attn[(size_t)b*T_ + t];
  float acc[6] = {0,0,0,0,0,0};
  #pragma unroll
  for (int k=0;k<8;++k){
    int j = lane*8 + k;
    float ov = bf2f(ob[k]);
    ov = (ov >= 0.f) ? ov : alpha*ov;
    float d = db[j];
    const float* dwp = dw + (size_t)j*12;
    #pragma unroll
    for (int i=0;i<12;++i) d += xr[i]*dwp[i];
    float uo = ov + av*d;
    #pragma unroll
    for (int o=0;o<3;++o){
      acc[o]   += uo * vw[(size_t)o*H_ + j];
      acc[3+o] += uo * swt[(size_t)o*H_ + j];
    }
  }
  #pragma unroll
  for (int o=0;o<6;++o){
    #pragma unroll
    for (int off=32; off>0; off>>=1) acc[o] += __shfl_xor(acc[o], off, 64);
  }
  if (lane == 0){
    size_t p = ((size_t)b*T_ + t)*3;
    #pragma unroll
    for (int o=0;o<3;++o){
      dout[p + o] = acc[o] + vb[o];
      dout[(size_t)B_*T_*3 + p + o] = acc[3+o] + sb[o];
    }
  }
}

extern "C" void kernel_launch(void* const* d_in, const int* in_sizes, int n_in,
                              void* d_out, int out_size, void* d_ws, size_t ws_size,
                              hipStream_t stream)
{
  (void)in_sizes; (void)n_in; (void)out_size; (void)ws_size;
  const float* x        = (const float*)d_in[0];
  const float* vel_init = (const float*)d_in[1];
  const float* w_ih[3] = {(const float*)d_in[2], (const float*)d_in[6],  (const float*)d_in[10]};
  const float* w_hh[3] = {(const float*)d_in[3], (const float*)d_in[7],  (const float*)d_in[11]};
  const float* b_ih[3] = {(const float*)d_in[4], (const float*)d_in[8],  (const float*)d_in[12]};
  const float* b_hh[3] = {(const float*)d_in[5], (const float*)d_in[9],  (const float*)d_in[13]};
  const float* a1     = (const float*)d_in[14];
  const float* dec_w  = (const float*)d_in[15];
  const float* dec_b  = (const float*)d_in[16];
  const float* vd_w[3] = {(const float*)d_in[17], (const float*)d_in[19], (const float*)d_in[21]};
  const float* vd_b[3] = {(const float*)d_in[18], (const float*)d_in[20], (const float*)d_in[22]};
  const float* vel_w  = (const float*)d_in[23];
  const float* vel_b  = (const float*)d_in[24];
  const float* std_w  = (const float*)d_in[25];
  const float* std_b  = (const float*)d_in[26];
  const float* attn_w = (const float*)d_in[27];
  const float* attn_b = (const float*)d_in[28];

  char* ws = (char*)d_ws;                         // ~76.4 MB used
  uint16_t* out2   = (uint16_t*)(ws);                      // 64 MB
  uint16_t* ring0  = (uint16_t*)(ws + (size_t)67108864);   // 4 MB
  uint16_t* ring1  = (uint16_t*)(ws + (size_t)71303168);   // 4 MB
  float*    h0f    = (float*)   (ws + (size_t)75497472);   // 192 KB
  uint16_t* h0b    = (uint16_t*)(ws + (size_t)75694080);   // 96 KB
  float*    scores = (float*)   (ws + (size_t)75792384);   // 256 KB
  float*    attnp  = (float*)   (ws + (size_t)76054528);   // 256 KB
  uint32_t* progress = (uint32_t*)(ws + (size_t)76316672); // 768 B

  // sentinel-poison out2 + both rings (contiguous 72 MB), every call
  poison_kernel<<<2048, 256, 0, stream>>>((uint32_t*)ws, 72u*1024u*1024u/16u);
  init_kernel<<<3, 256, 0, stream>>>(vel_init, vd_w[0], vd_b[0], vd_w[1], vd_b[1],
                                     vd_w[2], vd_b[2], h0f, h0b, progress);

  ScanParams P;
  P.x = x;
  for (int l=0;l<3;++l){ P.wih[l]=w_ih[l]; P.whh[l]=w_hh[l]; P.bih[l]=b_ih[l]; P.bhh[l]=b_hh[l]; }
  P.h0f = h0f; P.h0b = h0b;
  P.ring0 = ring0; P.ring1 = ring1; P.out2 = out2; P.progress = progress;

  fused_scan<<<96, 128, 0, stream>>>(P);

  scores_kernel<<<(B_*T_)/4, 256, 0, stream>>>(out2, attn_w, attn_b, a1, scores);
  softmax_kernel<<<B_, 256, 0, stream>>>(scores, attnp);
  final_kernel<<<(B_*T_)/4, 256, 0, stream>>>(out2, x, attnp, dec_w, dec_b,
                                              vel_w, vel_b, std_w, std_b, a1, (float*)d_out);
}